// Round 1
// baseline (1052.231 us; speedup 1.0000x reference)
//
#include <hip/hip_runtime.h>

// GraphSAGE fwd: h=XW_in^T+b; deg; 2x [agg(mean) -> h@Ws^T+b+hn@Wn^T -> lrelu]; out=h@Wo^T+bo
// ws layout (bytes):
//   h        : 0            .. 51,200,000   (100000*128 f32)
//   hn       : 51,200,000   .. 102,400,000
//   deg(int) : 102,400,000  .. 102,800,000
//   inv_deg  : 102,800,000  .. 103,200,000
//   row_start: 103,200,000  .. 103,600,016  (100001 ints, padded)
//   cursor   : 103,600,016  .. 104,000,016
//   csr_src  : 104,000,016  .. 110,400,016  (1.6M ints)
//   bsums    : 110,400,016  .. +256
//   boffs    : 110,400,272  .. +256
// total ~110.5 MB

#define N_NODES 100000
#define N_EDGES 1600000
#define IN_FEATS 512
#define HIDDEN 128
#define NEG_SLOPE 0.01f
#define SCAN_BLOCKS 49  // ceil(100000/2048)

__global__ __launch_bounds__(256) void k_degree(const int* __restrict__ dst,
                                                int* __restrict__ deg) {
  int e = blockIdx.x * 256 + threadIdx.x;
  if (e < N_EDGES) atomicAdd(&deg[dst[e]], 1);
}

__device__ __forceinline__ int wave_incl_scan(int v) {
  #pragma unroll
  for (int d = 1; d < 64; d <<= 1) {
    int t = __shfl_up(v, d, 64);
    if ((threadIdx.x & 63) >= d) v += t;
  }
  return v;
}

// per-block exclusive scan of deg -> out (partial), block totals -> bsums
__global__ __launch_bounds__(256) void k_scanA(const int* __restrict__ deg,
                                               int* __restrict__ out,
                                               int* __restrict__ bsums) {
  __shared__ int wsum[4];
  int base = blockIdx.x * 2048 + threadIdx.x * 8;
  int v[8];
  int s = 0;
  #pragma unroll
  for (int i = 0; i < 8; i++) {
    int idx = base + i;
    v[i] = (idx < N_NODES) ? deg[idx] : 0;
    s += v[i];
  }
  int incl = wave_incl_scan(s);
  int wid = threadIdx.x >> 6;
  if ((threadIdx.x & 63) == 63) wsum[wid] = incl;
  __syncthreads();
  int woff = 0;
  #pragma unroll
  for (int w = 0; w < 4; w++)
    if (w < wid) woff += wsum[w];
  int run = woff + incl - s;  // exclusive start for this thread
  #pragma unroll
  for (int i = 0; i < 8; i++) {
    int idx = base + i;
    if (idx < N_NODES) out[idx] = run;
    run += v[i];
  }
  if (threadIdx.x == 255) bsums[blockIdx.x] = woff + incl;
}

__global__ __launch_bounds__(64) void k_scanB(const int* __restrict__ bsums,
                                              int* __restrict__ boffs) {
  int t = threadIdx.x;
  int v = (t < SCAN_BLOCKS) ? bsums[t] : 0;
  int incl = wave_incl_scan(v);
  if (t < SCAN_BLOCKS) boffs[t] = incl - v;
}

// add block offsets; produce row_start, cursor, inv_deg
__global__ __launch_bounds__(256) void k_scanC(const int* __restrict__ deg,
                                               int* __restrict__ row_start,
                                               int* __restrict__ cursor,
                                               float* __restrict__ inv_deg,
                                               const int* __restrict__ boffs) {
  int b = boffs[blockIdx.x];
  int base = blockIdx.x * 2048 + threadIdx.x * 8;
  #pragma unroll
  for (int i = 0; i < 8; i++) {
    int idx = base + i;
    if (idx < N_NODES) {
      int rs = row_start[idx] + b;
      row_start[idx] = rs;
      cursor[idx] = rs;
      int d = deg[idx];
      inv_deg[idx] = 1.0f / (float)(d > 1 ? d : 1);
    }
  }
  if (blockIdx.x == 0 && threadIdx.x == 0) row_start[N_NODES] = N_EDGES;
}

__global__ __launch_bounds__(256) void k_fill(const int* __restrict__ src,
                                              const int* __restrict__ dst,
                                              int* __restrict__ cursor,
                                              int* __restrict__ csr_src) {
  int e = blockIdx.x * 256 + threadIdx.x;
  if (e < N_EDGES) {
    int d = dst[e];
    int p = atomicAdd(&cursor[d], 1);
    csr_src[p] = src[e];
  }
}

// C[i][col] = sum_k A1[i][k]*W1[col][k] (+ A2/W2 for virtual K2) + bias[col], opt leaky-relu
// A1:[N x K1] ld K1, W1:[128 x K1] ld K1, A2/W2 analogous with K2. C: [N x 128].
template <int K1, int K2, bool RELU>
__global__ __launch_bounds__(256) void k_gemm(const float* __restrict__ A1,
                                              const float* __restrict__ A2,
                                              const float* __restrict__ W1,
                                              const float* __restrict__ W2,
                                              const float* __restrict__ bias,
                                              float* __restrict__ C) {
  constexpr int BM = 64, BN = 128, BK = 32;
  constexpr int KT = (K1 + K2) / BK;
  __shared__ float As[BM][36];    // row-major, pad->2-way max (free)
  __shared__ float Bs[BK][132];   // [k][col], pad 132 keeps float4 16B-aligned
  const int tid = threadIdx.x;
  const int tx = tid & 31;   // col group: cols tx*4..+3
  const int ty = tid >> 5;   // row group: rows ty*8..+7
  const int r0 = blockIdx.x * BM;

  float acc[8][4];
  #pragma unroll
  for (int r = 0; r < 8; r++)
    #pragma unroll
    for (int c = 0; c < 4; c++) acc[r][c] = 0.f;

  const float4 bias4 = *(const float4*)&bias[tx * 4];

  const int quad = tid & 7;      // k-quad within BK
  const int rowb = tid >> 3;     // 0..31

  for (int kt = 0; kt < KT; ++kt) {
    const float* Ap;
    const float* Wp;
    int k0, lda;
    if (K2 == 0 || kt * BK < K1) {
      Ap = A1; Wp = W1; k0 = kt * BK; lda = K1;
    } else {
      Ap = A2; Wp = W2; k0 = kt * BK - K1; lda = K2;
    }
    // stage A tile: 64 rows x 32 k, 2 float4/thread
    #pragma unroll
    for (int i = 0; i < 2; i++) {
      int rr = rowb + i * 32;
      int gr = r0 + rr;
      float4 v = make_float4(0.f, 0.f, 0.f, 0.f);
      if (gr < N_NODES) v = *(const float4*)&Ap[(long)gr * lda + k0 + quad * 4];
      *(float4*)&As[rr][quad * 4] = v;
    }
    // stage B tile transposed: Bs[k][col] = W[col][k], 4 cols/thread
    #pragma unroll
    for (int i = 0; i < 4; i++) {
      int col = rowb + i * 32;
      float4 v = *(const float4*)&Wp[(long)col * lda + k0 + quad * 4];
      Bs[quad * 4 + 0][col] = v.x;
      Bs[quad * 4 + 1][col] = v.y;
      Bs[quad * 4 + 2][col] = v.z;
      Bs[quad * 4 + 3][col] = v.w;
    }
    __syncthreads();

    #pragma unroll
    for (int kk = 0; kk < BK; kk += 4) {
      float4 b4[4];
      #pragma unroll
      for (int j = 0; j < 4; j++) b4[j] = *(const float4*)&Bs[kk + j][tx * 4];
      float4 a4[8];
      #pragma unroll
      for (int r = 0; r < 8; r++) a4[r] = *(const float4*)&As[ty * 8 + r][kk];
      #pragma unroll
      for (int j = 0; j < 4; j++) {
        #pragma unroll
        for (int r = 0; r < 8; r++) {
          float av = (j == 0) ? a4[r].x : (j == 1) ? a4[r].y : (j == 2) ? a4[r].z : a4[r].w;
          acc[r][0] += av * b4[j].x;
          acc[r][1] += av * b4[j].y;
          acc[r][2] += av * b4[j].z;
          acc[r][3] += av * b4[j].w;
        }
      }
    }
    __syncthreads();
  }

  #pragma unroll
  for (int r = 0; r < 8; r++) {
    int gr = r0 + ty * 8 + r;
    if (gr < N_NODES) {
      float4 v;
      v.x = acc[r][0] + bias4.x;
      v.y = acc[r][1] + bias4.y;
      v.z = acc[r][2] + bias4.z;
      v.w = acc[r][3] + bias4.w;
      if (RELU) {
        v.x = v.x > 0.f ? v.x : v.x * NEG_SLOPE;
        v.y = v.y > 0.f ? v.y : v.y * NEG_SLOPE;
        v.z = v.z > 0.f ? v.z : v.z * NEG_SLOPE;
        v.w = v.w > 0.f ? v.w : v.w * NEG_SLOPE;
      }
      *(float4*)&C[(long)gr * BN + tx * 4] = v;
    }
  }
}

// mean aggregation: 8 nodes/block, 32 lanes/node, float4 over 128 feats
__global__ __launch_bounds__(256) void k_agg(const float* __restrict__ h,
                                             const int* __restrict__ row_start,
                                             const int* __restrict__ csr_src,
                                             const float* __restrict__ inv_deg,
                                             float* __restrict__ hn) {
  int node = blockIdx.x * 8 + (threadIdx.x >> 5);
  int lane = threadIdx.x & 31;
  int s = row_start[node];
  int e = row_start[node + 1];
  float4 acc = make_float4(0.f, 0.f, 0.f, 0.f);
  for (int i = s; i < e; ++i) {
    int sn = csr_src[i];
    float4 v = *(const float4*)&h[sn * HIDDEN + lane * 4];
    acc.x += v.x; acc.y += v.y; acc.z += v.z; acc.w += v.w;
  }
  float id = inv_deg[node];
  acc.x *= id; acc.y *= id; acc.z *= id; acc.w *= id;
  *(float4*)&hn[node * HIDDEN + lane * 4] = acc;
}

// out[n][c] = h[n] . W_out[c] + b_out[c]; wave per node (4/block)
__global__ __launch_bounds__(256) void k_out(const float* __restrict__ h,
                                             const float* __restrict__ W_out,
                                             const float* __restrict__ b_out,
                                             float* __restrict__ out) {
  int node = blockIdx.x * 4 + (threadIdx.x >> 6);
  int l = threadIdx.x & 63;
  float a = h[node * HIDDEN + l];
  float b = h[node * HIDDEN + 64 + l];
  float s0 = a * W_out[l] + b * W_out[64 + l];
  float s1 = a * W_out[128 + l] + b * W_out[192 + l];
  #pragma unroll
  for (int d = 32; d >= 1; d >>= 1) {
    s0 += __shfl_xor(s0, d, 64);
    s1 += __shfl_xor(s1, d, 64);
  }
  if (l == 0) {
    out[node * 2 + 0] = s0 + b_out[0];
    out[node * 2 + 1] = s1 + b_out[1];
  }
}

extern "C" void kernel_launch(void* const* d_in, const int* in_sizes, int n_in,
                              void* d_out, int out_size, void* d_ws, size_t ws_size,
                              hipStream_t stream) {
  const float* features = (const float*)d_in[0];
  const int* src = (const int*)d_in[1];
  const int* dst = (const int*)d_in[2];
  const float* W_in = (const float*)d_in[3];
  const float* b_in = (const float*)d_in[4];
  const float* W_self = (const float*)d_in[5];
  const float* b_self = (const float*)d_in[6];
  const float* W_neigh = (const float*)d_in[7];
  const float* W_out = (const float*)d_in[8];
  const float* b_out = (const float*)d_in[9];
  float* out = (float*)d_out;

  char* ws = (char*)d_ws;
  float* h = (float*)(ws + 0);
  float* hn = (float*)(ws + 51200000);
  int* deg = (int*)(ws + 102400000);
  float* inv_deg = (float*)(ws + 102800000);
  int* row_start = (int*)(ws + 103200000);
  int* cursor = (int*)(ws + 103600016);
  int* csr_src = (int*)(ws + 104000016);
  int* bsums = (int*)(ws + 110400016);
  int* boffs = (int*)(ws + 110400272);

  hipMemsetAsync(deg, 0, N_NODES * sizeof(int), stream);
  k_degree<<<6250, 256, 0, stream>>>(dst, deg);
  k_scanA<<<SCAN_BLOCKS, 256, 0, stream>>>(deg, row_start, bsums);
  k_scanB<<<1, 64, 0, stream>>>(bsums, boffs);
  k_scanC<<<SCAN_BLOCKS, 256, 0, stream>>>(deg, row_start, cursor, inv_deg, boffs);
  k_fill<<<6250, 256, 0, stream>>>(src, dst, cursor, csr_src);

  // input projection: h = features @ W_in^T + b_in
  k_gemm<IN_FEATS, 0, false><<<1563, 256, 0, stream>>>(features, nullptr, W_in,
                                                       nullptr, b_in, h);
  for (int l = 0; l < 2; ++l) {
    k_agg<<<12500, 256, 0, stream>>>(h, row_start, csr_src, inv_deg, hn);
    k_gemm<HIDDEN, HIDDEN, true><<<1563, 256, 0, stream>>>(
        h, hn, W_self + l * HIDDEN * HIDDEN, W_neigh + l * HIDDEN * HIDDEN,
        b_self + l * HIDDEN, h);
  }
  k_out<<<25000, 256, 0, stream>>>(h, W_out, b_out, out);
}

// Round 2
// 866.696 us; speedup vs baseline: 1.2141x; 1.2141x over previous
//
#include <hip/hip_runtime.h>

// GraphSAGE fwd: h=XW_in^T+b; deg; 2x [agg(mean) -> h@Ws^T+b+hn@Wn^T -> lrelu]; out=h@Wo^T+bo
// GEMMs via split-bf16 MFMA (hi/lo error compensation, 3 MFMA per product term).
// ws layout (bytes):
//   h        : 0            .. 51,200,000   (100000*128 f32)
//   hn       : 51,200,000   .. 102,400,000
//   deg(int) : 102,400,000  .. 102,800,000
//   inv_deg  : 102,800,000  .. 103,200,000
//   row_start: 103,200,000  .. 103,600,016  (100001 ints, padded)
//   cursor   : 103,600,016  .. 104,000,016
//   csr_src  : 104,000,016  .. 110,400,016  (1.6M ints)
//   bsums    : 110,400,016  .. +256
//   boffs    : 110,400,272  .. +256

#define N_NODES 100000
#define N_EDGES 1600000
#define IN_FEATS 512
#define HIDDEN 128
#define NEG_SLOPE 0.01f
#define SCAN_BLOCKS 49  // ceil(100000/2048)

typedef __attribute__((ext_vector_type(8))) __bf16 bf16x8;
typedef __attribute__((ext_vector_type(4))) __bf16 bf16x4;
typedef __attribute__((ext_vector_type(4))) float f32x4;

__global__ __launch_bounds__(256) void k_degree(const int* __restrict__ dst,
                                                int* __restrict__ deg) {
  int e = blockIdx.x * 256 + threadIdx.x;
  if (e < N_EDGES) atomicAdd(&deg[dst[e]], 1);
}

__device__ __forceinline__ int wave_incl_scan(int v) {
  #pragma unroll
  for (int d = 1; d < 64; d <<= 1) {
    int t = __shfl_up(v, d, 64);
    if ((threadIdx.x & 63) >= d) v += t;
  }
  return v;
}

__global__ __launch_bounds__(256) void k_scanA(const int* __restrict__ deg,
                                               int* __restrict__ out,
                                               int* __restrict__ bsums) {
  __shared__ int wsum[4];
  int base = blockIdx.x * 2048 + threadIdx.x * 8;
  int v[8];
  int s = 0;
  #pragma unroll
  for (int i = 0; i < 8; i++) {
    int idx = base + i;
    v[i] = (idx < N_NODES) ? deg[idx] : 0;
    s += v[i];
  }
  int incl = wave_incl_scan(s);
  int wid = threadIdx.x >> 6;
  if ((threadIdx.x & 63) == 63) wsum[wid] = incl;
  __syncthreads();
  int woff = 0;
  #pragma unroll
  for (int w = 0; w < 4; w++)
    if (w < wid) woff += wsum[w];
  int run = woff + incl - s;
  #pragma unroll
  for (int i = 0; i < 8; i++) {
    int idx = base + i;
    if (idx < N_NODES) out[idx] = run;
    run += v[i];
  }
  if (threadIdx.x == 255) bsums[blockIdx.x] = woff + incl;
}

__global__ __launch_bounds__(64) void k_scanB(const int* __restrict__ bsums,
                                              int* __restrict__ boffs) {
  int t = threadIdx.x;
  int v = (t < SCAN_BLOCKS) ? bsums[t] : 0;
  int incl = wave_incl_scan(v);
  if (t < SCAN_BLOCKS) boffs[t] = incl - v;
}

__global__ __launch_bounds__(256) void k_scanC(const int* __restrict__ deg,
                                               int* __restrict__ row_start,
                                               int* __restrict__ cursor,
                                               float* __restrict__ inv_deg,
                                               const int* __restrict__ boffs) {
  int b = boffs[blockIdx.x];
  int base = blockIdx.x * 2048 + threadIdx.x * 8;
  #pragma unroll
  for (int i = 0; i < 8; i++) {
    int idx = base + i;
    if (idx < N_NODES) {
      int rs = row_start[idx] + b;
      row_start[idx] = rs;
      cursor[idx] = rs;
      int d = deg[idx];
      inv_deg[idx] = 1.0f / (float)(d > 1 ? d : 1);
    }
  }
  if (blockIdx.x == 0 && threadIdx.x == 0) row_start[N_NODES] = N_EDGES;
}

__global__ __launch_bounds__(256) void k_fill(const int* __restrict__ src,
                                              const int* __restrict__ dst,
                                              int* __restrict__ cursor,
                                              int* __restrict__ csr_src) {
  int e = blockIdx.x * 256 + threadIdx.x;
  if (e < N_EDGES) {
    int d = dst[e];
    int p = atomicAdd(&cursor[d], 1);
    csr_src[p] = src[e];
  }
}

// ---------------- split-bf16 MFMA GEMM ----------------
// C[i][col] = sum_k A[i][k]*W[col][k] + bias[col], optional leaky-relu.
// Virtual K = K1 (A1/W1) then K2 (A2/W2). BM=128, BN=128(=full N), BK=32.
// 4 waves in 2x2; each wave 64x64 = 4x4 frags of mfma_f32_16x16x32_bf16.
// fp32 -> (hi,lo) bf16 split during staging; 3 MFMAs per (a,b) frag pair.
// LDS rows padded 32->40 bf16 (80B): ds_read_b128 2-way max (free).
template <int K1, int K2, bool RELU>
__global__ __launch_bounds__(256) void k_gemm(const float* __restrict__ A1,
                                              const float* __restrict__ A2,
                                              const float* __restrict__ W1,
                                              const float* __restrict__ W2,
                                              const float* __restrict__ bias,
                                              float* __restrict__ C) {
  constexpr int BK = 32;
  constexpr int KT = (K1 + K2) / BK;
  constexpr int LP = 40;  // padded row length in bf16
  __shared__ __bf16 As_h[128 * LP];
  __shared__ __bf16 As_l[128 * LP];
  __shared__ __bf16 Bs_h[128 * LP];
  __shared__ __bf16 Bs_l[128 * LP];

  const int tid = threadIdx.x;
  const int lane = tid & 63;
  const int wid = tid >> 6;
  const int wr = wid >> 1;   // wave row (0..1) -> 64-row half
  const int wc = wid & 1;    // wave col (0..1) -> 64-col half
  const int lr = lane & 15;  // row/col within 16x16 frag
  const int kg = lane >> 4;  // k-group: lane reads k = 8*kg..8*kg+7
  const int r0 = blockIdx.x * 128;

  f32x4 acc[4][4];
  #pragma unroll
  for (int m = 0; m < 4; m++)
    #pragma unroll
    for (int n = 0; n < 4; n++) acc[m][n] = (f32x4){0.f, 0.f, 0.f, 0.f};

  float4 ra[4], rb[4];

  // load tile kt into registers
  auto load_tile = [&](int kt) {
    const float* Ap;
    const float* Wp;
    int k0, lda;
    if (K2 == 0 || kt * BK < K1) {
      Ap = A1; Wp = W1; k0 = kt * BK; lda = K1;
    } else {
      Ap = A2; Wp = W2; k0 = kt * BK - K1; lda = K2;
    }
    #pragma unroll
    for (int i = 0; i < 4; i++) {
      int flat = i * 256 + tid;
      int row = flat >> 3;   // 0..127
      int q = flat & 7;      // float4 index within 32-k row
      int gr = r0 + row;
      ra[i] = (gr < N_NODES) ? *(const float4*)&Ap[(long)gr * lda + k0 + q * 4]
                             : make_float4(0.f, 0.f, 0.f, 0.f);
      rb[i] = *(const float4*)&Wp[(long)row * lda + k0 + q * 4];
    }
  };

  auto split_write = [&](float v, __bf16* hp, __bf16* lp, int off) {
    __bf16 h = (__bf16)v;
    float rem = v - (float)h;
    hp[off] = h;
    lp[off] = (__bf16)rem;
  };

  load_tile(0);

  for (int kt = 0; kt < KT; ++kt) {
    if (kt > 0) __syncthreads();  // prior compute done reading LDS
    // convert + write staged regs to LDS
    #pragma unroll
    for (int i = 0; i < 4; i++) {
      int flat = i * 256 + tid;
      int row = flat >> 3;
      int q = flat & 7;
      int off = row * LP + q * 4;
      split_write(ra[i].x, As_h, As_l, off + 0);
      split_write(ra[i].y, As_h, As_l, off + 1);
      split_write(ra[i].z, As_h, As_l, off + 2);
      split_write(ra[i].w, As_h, As_l, off + 3);
      split_write(rb[i].x, Bs_h, Bs_l, off + 0);
      split_write(rb[i].y, Bs_h, Bs_l, off + 1);
      split_write(rb[i].z, Bs_h, Bs_l, off + 2);
      split_write(rb[i].w, Bs_h, Bs_l, off + 3);
    }
    __syncthreads();
    if (kt + 1 < KT) load_tile(kt + 1);  // prefetch next tile (hides HBM under MFMA)

    bf16x8 ah[4], al[4];
    #pragma unroll
    for (int m = 0; m < 4; m++) {
      int arow = wr * 64 + m * 16 + lr;
      ah[m] = *(const bf16x8*)&As_h[arow * LP + kg * 8];
      al[m] = *(const bf16x8*)&As_l[arow * LP + kg * 8];
    }
    #pragma unroll
    for (int n = 0; n < 4; n++) {
      int bcol = wc * 64 + n * 16 + lr;
      bf16x8 bh = *(const bf16x8*)&Bs_h[bcol * LP + kg * 8];
      bf16x8 bl = *(const bf16x8*)&Bs_l[bcol * LP + kg * 8];
      #pragma unroll
      for (int m = 0; m < 4; m++) {
        acc[m][n] = __builtin_amdgcn_mfma_f32_16x16x32_bf16(ah[m], bh, acc[m][n], 0, 0, 0);
        acc[m][n] = __builtin_amdgcn_mfma_f32_16x16x32_bf16(al[m], bh, acc[m][n], 0, 0, 0);
        acc[m][n] = __builtin_amdgcn_mfma_f32_16x16x32_bf16(ah[m], bl, acc[m][n], 0, 0, 0);
      }
    }
  }

  // epilogue: C[row][col], col = lane&15 (+16n+64wc), row = 4*(lane>>4)+j (+16m+64wr)
  #pragma unroll
  for (int n = 0; n < 4; n++) {
    int col = wc * 64 + n * 16 + lr;
    float bc = bias[col];
    #pragma unroll
    for (int m = 0; m < 4; m++) {
      int rowb = r0 + wr * 64 + m * 16 + kg * 4;
      #pragma unroll
      for (int j = 0; j < 4; j++) {
        int row = rowb + j;
        if (row < N_NODES) {
          float v = acc[m][n][j] + bc;
          if (RELU) v = v > 0.f ? v : v * NEG_SLOPE;
          C[(long)row * 128 + col] = v;
        }
      }
    }
  }
}

// mean aggregation: 8 nodes/block, 32 lanes/node, float4 over 128 feats
__global__ __launch_bounds__(256) void k_agg(const float* __restrict__ h,
                                             const int* __restrict__ row_start,
                                             const int* __restrict__ csr_src,
                                             const float* __restrict__ inv_deg,
                                             float* __restrict__ hn) {
  int node = blockIdx.x * 8 + (threadIdx.x >> 5);
  int lane = threadIdx.x & 31;
  int s = row_start[node];
  int e = row_start[node + 1];
  float4 acc = make_float4(0.f, 0.f, 0.f, 0.f);
  for (int i = s; i < e; ++i) {
    int sn = csr_src[i];
    float4 v = *(const float4*)&h[sn * HIDDEN + lane * 4];
    acc.x += v.x; acc.y += v.y; acc.z += v.z; acc.w += v.w;
  }
  float id = inv_deg[node];
  acc.x *= id; acc.y *= id; acc.z *= id; acc.w *= id;
  *(float4*)&hn[node * HIDDEN + lane * 4] = acc;
}

// out[n][c] = h[n] . W_out[c] + b_out[c]; wave per node (4/block)
__global__ __launch_bounds__(256) void k_out(const float* __restrict__ h,
                                             const float* __restrict__ W_out,
                                             const float* __restrict__ b_out,
                                             float* __restrict__ out) {
  int node = blockIdx.x * 4 + (threadIdx.x >> 6);
  int l = threadIdx.x & 63;
  float a = h[node * HIDDEN + l];
  float b = h[node * HIDDEN + 64 + l];
  float s0 = a * W_out[l] + b * W_out[64 + l];
  float s1 = a * W_out[128 + l] + b * W_out[192 + l];
  #pragma unroll
  for (int d = 32; d >= 1; d >>= 1) {
    s0 += __shfl_xor(s0, d, 64);
    s1 += __shfl_xor(s1, d, 64);
  }
  if (l == 0) {
    out[node * 2 + 0] = s0 + b_out[0];
    out[node * 2 + 1] = s1 + b_out[1];
  }
}

extern "C" void kernel_launch(void* const* d_in, const int* in_sizes, int n_in,
                              void* d_out, int out_size, void* d_ws, size_t ws_size,
                              hipStream_t stream) {
  const float* features = (const float*)d_in[0];
  const int* src = (const int*)d_in[1];
  const int* dst = (const int*)d_in[2];
  const float* W_in = (const float*)d_in[3];
  const float* b_in = (const float*)d_in[4];
  const float* W_self = (const float*)d_in[5];
  const float* b_self = (const float*)d_in[6];
  const float* W_neigh = (const float*)d_in[7];
  const float* W_out = (const float*)d_in[8];
  const float* b_out = (const float*)d_in[9];
  float* out = (float*)d_out;

  char* ws = (char*)d_ws;
  float* h = (float*)(ws + 0);
  float* hn = (float*)(ws + 51200000);
  int* deg = (int*)(ws + 102400000);
  float* inv_deg = (float*)(ws + 102800000);
  int* row_start = (int*)(ws + 103200000);
  int* cursor = (int*)(ws + 103600016);
  int* csr_src = (int*)(ws + 104000016);
  int* bsums = (int*)(ws + 110400016);
  int* boffs = (int*)(ws + 110400272);

  hipMemsetAsync(deg, 0, N_NODES * sizeof(int), stream);
  k_degree<<<6250, 256, 0, stream>>>(dst, deg);
  k_scanA<<<SCAN_BLOCKS, 256, 0, stream>>>(deg, row_start, bsums);
  k_scanB<<<1, 64, 0, stream>>>(bsums, boffs);
  k_scanC<<<SCAN_BLOCKS, 256, 0, stream>>>(deg, row_start, cursor, inv_deg, boffs);
  k_fill<<<6250, 256, 0, stream>>>(src, dst, cursor, csr_src);

  // input projection: h = features @ W_in^T + b_in   (782 = ceil(100000/128))
  k_gemm<IN_FEATS, 0, false><<<782, 256, 0, stream>>>(features, nullptr, W_in,
                                                      nullptr, b_in, h);
  for (int l = 0; l < 2; ++l) {
    k_agg<<<12500, 256, 0, stream>>>(h, row_start, csr_src, inv_deg, hn);
    k_gemm<HIDDEN, HIDDEN, true><<<782, 256, 0, stream>>>(
        h, hn, W_self + l * HIDDEN * HIDDEN, W_neigh + l * HIDDEN * HIDDEN,
        b_self + l * HIDDEN, h);
  }
  k_out<<<25000, 256, 0, stream>>>(h, W_out, b_out, out);
}

// Round 5
// 826.413 us; speedup vs baseline: 1.2733x; 1.0487x over previous
//
#include <hip/hip_runtime.h>

// GraphSAGE fwd: h=XW_in^T+b; deg; 2x [agg(mean) -> h@Ws^T+b+hn@Wn^T -> lrelu]; out=h@Wo^T+bo
// GEMMs via split-bf16 MFMA. CSR build via XCD-local ranged scatter (R2):
// dst-space split into 8 ranges; blocks with blockIdx%8==r own range r, so all
// scattered writes/atomics to a range's deg/cursor/csr region come from ONE XCD
// -> L2-resident, no cross-XCD line ping-pong (was 105MB HBM writes for 6.4MB data).
// ws layout (bytes):
//   h        : 0            .. 51,200,000   (100000*128 f32)
//   hn       : 51,200,000   .. 102,400,000
//   deg(int) : 102,400,000  .. 102,800,000
//   inv_deg  : 102,800,000  .. 103,200,000
//   row_start: 103,200,000  .. 103,600,016  (100001 ints, padded)
//   cursor   : 103,600,016  .. 104,000,016
//   csr_src  : 104,000,016  .. 110,400,016  (1.6M ints)
//   bsums    : 110,400,016  .. +256
//   boffs    : 110,400,272  .. +256

#define N_NODES 100000
#define N_EDGES 1600000
#define IN_FEATS 512
#define HIDDEN 128
#define NEG_SLOPE 0.01f
#define SCAN_BLOCKS 49  // ceil(100000/2048)

#define N_RANGES 8
#define RANGE_SZ 12500        // nodes per range (100000/8)
#define FILL_CHUNKS 256       // chunks per range
#define FILL_CHUNK 6250       // edges per chunk (1600000/256)

typedef __attribute__((ext_vector_type(8))) __bf16 bf16x8;
typedef __attribute__((ext_vector_type(4))) float f32x4;

// degree count, XCD-local: block (r = b&7, c = b>>3) filters dst in range r
__global__ __launch_bounds__(256) void k_degree(const int* __restrict__ dst,
                                                int* __restrict__ deg) {
  int r = blockIdx.x & 7;
  int c = blockIdx.x >> 3;
  int lo = r * RANGE_SZ, hi = lo + RANGE_SZ;
  int e0 = c * FILL_CHUNK;
  int e1 = e0 + FILL_CHUNK;
  if (e1 > N_EDGES) e1 = N_EDGES;
  for (int e = e0 + threadIdx.x; e < e1; e += 256) {
    int d = dst[e];
    if (d >= lo && d < hi) atomicAdd(&deg[d], 1);
  }
}

__device__ __forceinline__ int wave_incl_scan(int v) {
  #pragma unroll
  for (int d = 1; d < 64; d <<= 1) {
    int t = __shfl_up(v, d, 64);
    if ((threadIdx.x & 63) >= d) v += t;
  }
  return v;
}

__global__ __launch_bounds__(256) void k_scanA(const int* __restrict__ deg,
                                               int* __restrict__ out,
                                               int* __restrict__ bsums) {
  __shared__ int wsum[4];
  int base = blockIdx.x * 2048 + threadIdx.x * 8;
  int v[8];
  int s = 0;
  #pragma unroll
  for (int i = 0; i < 8; i++) {
    int idx = base + i;
    v[i] = (idx < N_NODES) ? deg[idx] : 0;
    s += v[i];
  }
  int incl = wave_incl_scan(s);
  int wid = threadIdx.x >> 6;
  if ((threadIdx.x & 63) == 63) wsum[wid] = incl;
  __syncthreads();
  int woff = 0;
  #pragma unroll
  for (int w = 0; w < 4; w++)
    if (w < wid) woff += wsum[w];
  int run = woff + incl - s;
  #pragma unroll
  for (int i = 0; i < 8; i++) {
    int idx = base + i;
    if (idx < N_NODES) out[idx] = run;
    run += v[i];
  }
  if (threadIdx.x == 255) bsums[blockIdx.x] = woff + incl;
}

__global__ __launch_bounds__(64) void k_scanB(const int* __restrict__ bsums,
                                              int* __restrict__ boffs) {
  int t = threadIdx.x;
  int v = (t < SCAN_BLOCKS) ? bsums[t] : 0;
  int incl = wave_incl_scan(v);
  if (t < SCAN_BLOCKS) boffs[t] = incl - v;
}

__global__ __launch_bounds__(256) void k_scanC(const int* __restrict__ deg,
                                               int* __restrict__ row_start,
                                               int* __restrict__ cursor,
                                               float* __restrict__ inv_deg,
                                               const int* __restrict__ boffs) {
  int b = boffs[blockIdx.x];
  int base = blockIdx.x * 2048 + threadIdx.x * 8;
  #pragma unroll
  for (int i = 0; i < 8; i++) {
    int idx = base + i;
    if (idx < N_NODES) {
      int rs = row_start[idx] + b;
      row_start[idx] = rs;
      cursor[idx] = rs;
      int d = deg[idx];
      inv_deg[idx] = 1.0f / (float)(d > 1 ? d : 1);
    }
  }
  if (blockIdx.x == 0 && threadIdx.x == 0) row_start[N_NODES] = N_EDGES;
}

// CSR bucket fill, XCD-local (same ranged structure as k_degree)
__global__ __launch_bounds__(256) void k_fill(const int* __restrict__ src,
                                              const int* __restrict__ dst,
                                              int* __restrict__ cursor,
                                              int* __restrict__ csr_src) {
  int r = blockIdx.x & 7;
  int c = blockIdx.x >> 3;
  int lo = r * RANGE_SZ, hi = lo + RANGE_SZ;
  int e0 = c * FILL_CHUNK;
  int e1 = e0 + FILL_CHUNK;
  if (e1 > N_EDGES) e1 = N_EDGES;
  for (int e = e0 + threadIdx.x; e < e1; e += 256) {
    int d = dst[e];
    if (d >= lo && d < hi) {
      int p = atomicAdd(&cursor[d], 1);
      csr_src[p] = src[e];
    }
  }
}

// ---------------- split-bf16 MFMA GEMM ----------------
// C[i][col] = sum_k A[i][k]*W[col][k] + bias[col], optional leaky-relu.
// Virtual K = K1 (A1/W1) then K2 (A2/W2). BM=128, BN=128(=full N), BK=32.
// 4 waves in 2x2; each wave 64x64 = 4x4 frags of mfma_f32_16x16x32_bf16.
// fp32 -> (hi,lo) bf16 split during staging; 3 MFMAs per (a,b) frag pair.
// LDS rows padded 32->40 bf16 (80B): ds_read_b128 2-way max (free).
template <int K1, int K2, bool RELU>
__global__ __launch_bounds__(256) void k_gemm(const float* __restrict__ A1,
                                              const float* __restrict__ A2,
                                              const float* __restrict__ W1,
                                              const float* __restrict__ W2,
                                              const float* __restrict__ bias,
                                              float* __restrict__ C) {
  constexpr int BK = 32;
  constexpr int KT = (K1 + K2) / BK;
  constexpr int LP = 40;  // padded row length in bf16
  __shared__ __bf16 As_h[128 * LP];
  __shared__ __bf16 As_l[128 * LP];
  __shared__ __bf16 Bs_h[128 * LP];
  __shared__ __bf16 Bs_l[128 * LP];

  const int tid = threadIdx.x;
  const int lane = tid & 63;
  const int wid = tid >> 6;
  const int wr = wid >> 1;   // wave row (0..1) -> 64-row half
  const int wc = wid & 1;    // wave col (0..1) -> 64-col half
  const int lr = lane & 15;  // row/col within 16x16 frag
  const int kg = lane >> 4;  // k-group: lane reads k = 8*kg..8*kg+7
  const int r0 = blockIdx.x * 128;

  f32x4 acc[4][4];
  #pragma unroll
  for (int m = 0; m < 4; m++)
    #pragma unroll
    for (int n = 0; n < 4; n++) acc[m][n] = (f32x4){0.f, 0.f, 0.f, 0.f};

  float4 ra[4], rb[4];

  auto load_tile = [&](int kt) {
    const float* Ap;
    const float* Wp;
    int k0, lda;
    if (K2 == 0 || kt * BK < K1) {
      Ap = A1; Wp = W1; k0 = kt * BK; lda = K1;
    } else {
      Ap = A2; Wp = W2; k0 = kt * BK - K1; lda = K2;
    }
    #pragma unroll
    for (int i = 0; i < 4; i++) {
      int flat = i * 256 + tid;
      int row = flat >> 3;   // 0..127
      int q = flat & 7;      // float4 index within 32-k row
      int gr = r0 + row;
      ra[i] = (gr < N_NODES) ? *(const float4*)&Ap[(long)gr * lda + k0 + q * 4]
                             : make_float4(0.f, 0.f, 0.f, 0.f);
      rb[i] = *(const float4*)&Wp[(long)row * lda + k0 + q * 4];
    }
  };

  auto split_write = [&](float v, __bf16* hp, __bf16* lp, int off) {
    __bf16 h = (__bf16)v;
    float rem = v - (float)h;
    hp[off] = h;
    lp[off] = (__bf16)rem;
  };

  load_tile(0);

  for (int kt = 0; kt < KT; ++kt) {
    if (kt > 0) __syncthreads();  // prior compute done reading LDS
    #pragma unroll
    for (int i = 0; i < 4; i++) {
      int flat = i * 256 + tid;
      int row = flat >> 3;
      int q = flat & 7;
      int off = row * LP + q * 4;
      split_write(ra[i].x, As_h, As_l, off + 0);
      split_write(ra[i].y, As_h, As_l, off + 1);
      split_write(ra[i].z, As_h, As_l, off + 2);
      split_write(ra[i].w, As_h, As_l, off + 3);
      split_write(rb[i].x, Bs_h, Bs_l, off + 0);
      split_write(rb[i].y, Bs_h, Bs_l, off + 1);
      split_write(rb[i].z, Bs_h, Bs_l, off + 2);
      split_write(rb[i].w, Bs_h, Bs_l, off + 3);
    }
    __syncthreads();
    if (kt + 1 < KT) load_tile(kt + 1);  // prefetch next tile (hides HBM under MFMA)

    bf16x8 ah[4], al[4];
    #pragma unroll
    for (int m = 0; m < 4; m++) {
      int arow = wr * 64 + m * 16 + lr;
      ah[m] = *(const bf16x8*)&As_h[arow * LP + kg * 8];
      al[m] = *(const bf16x8*)&As_l[arow * LP + kg * 8];
    }
    #pragma unroll
    for (int n = 0; n < 4; n++) {
      int bcol = wc * 64 + n * 16 + lr;
      bf16x8 bh = *(const bf16x8*)&Bs_h[bcol * LP + kg * 8];
      bf16x8 bl = *(const bf16x8*)&Bs_l[bcol * LP + kg * 8];
      #pragma unroll
      for (int m = 0; m < 4; m++) {
        acc[m][n] = __builtin_amdgcn_mfma_f32_16x16x32_bf16(ah[m], bh, acc[m][n], 0, 0, 0);
        acc[m][n] = __builtin_amdgcn_mfma_f32_16x16x32_bf16(al[m], bh, acc[m][n], 0, 0, 0);
        acc[m][n] = __builtin_amdgcn_mfma_f32_16x16x32_bf16(ah[m], bl, acc[m][n], 0, 0, 0);
      }
    }
  }

  // epilogue: C[row][col], col = lane&15 (+16n+64wc), row = 4*(lane>>4)+j (+16m+64wr)
  #pragma unroll
  for (int n = 0; n < 4; n++) {
    int col = wc * 64 + n * 16 + lr;
    float bc = bias[col];
    #pragma unroll
    for (int m = 0; m < 4; m++) {
      int rowb = r0 + wr * 64 + m * 16 + kg * 4;
      #pragma unroll
      for (int j = 0; j < 4; j++) {
        int row = rowb + j;
        if (row < N_NODES) {
          float v = acc[m][n][j] + bc;
          if (RELU) v = v > 0.f ? v : v * NEG_SLOPE;
          C[(long)row * 128 + col] = v;
        }
      }
    }
  }
}

// mean aggregation: 8 nodes/block, 32 lanes/node, float4 over 128 feats
__global__ __launch_bounds__(256) void k_agg(const float* __restrict__ h,
                                             const int* __restrict__ row_start,
                                             const int* __restrict__ csr_src,
                                             const float* __restrict__ inv_deg,
                                             float* __restrict__ hn) {
  int node = blockIdx.x * 8 + (threadIdx.x >> 5);
  int lane = threadIdx.x & 31;
  int s = row_start[node];
  int e = row_start[node + 1];
  float4 acc = make_float4(0.f, 0.f, 0.f, 0.f);
  for (int i = s; i < e; ++i) {
    int sn = csr_src[i];
    float4 v = *(const float4*)&h[sn * HIDDEN + lane * 4];
    acc.x += v.x; acc.y += v.y; acc.z += v.z; acc.w += v.w;
  }
  float id = inv_deg[node];
  acc.x *= id; acc.y *= id; acc.z *= id; acc.w *= id;
  *(float4*)&hn[node * HIDDEN + lane * 4] = acc;
}

// out[n][c] = h[n] . W_out[c] + b_out[c]; wave per node (4/block)
__global__ __launch_bounds__(256) void k_out(const float* __restrict__ h,
                                             const float* __restrict__ W_out,
                                             const float* __restrict__ b_out,
                                             float* __restrict__ out) {
  int node = blockIdx.x * 4 + (threadIdx.x >> 6);
  int l = threadIdx.x & 63;
  float a = h[node * HIDDEN + l];
  float b = h[node * HIDDEN + 64 + l];
  float s0 = a * W_out[l] + b * W_out[64 + l];
  float s1 = a * W_out[128 + l] + b * W_out[192 + l];
  #pragma unroll
  for (int d = 32; d >= 1; d >>= 1) {
    s0 += __shfl_xor(s0, d, 64);
    s1 += __shfl_xor(s1, d, 64);
  }
  if (l == 0) {
    out[node * 2 + 0] = s0 + b_out[0];
    out[node * 2 + 1] = s1 + b_out[1];
  }
}

extern "C" void kernel_launch(void* const* d_in, const int* in_sizes, int n_in,
                              void* d_out, int out_size, void* d_ws, size_t ws_size,
                              hipStream_t stream) {
  const float* features = (const float*)d_in[0];
  const int* src = (const int*)d_in[1];
  const int* dst = (const int*)d_in[2];
  const float* W_in = (const float*)d_in[3];
  const float* b_in = (const float*)d_in[4];
  const float* W_self = (const float*)d_in[5];
  const float* b_self = (const float*)d_in[6];
  const float* W_neigh = (const float*)d_in[7];
  const float* W_out = (const float*)d_in[8];
  const float* b_out = (const float*)d_in[9];
  float* out = (float*)d_out;

  char* ws = (char*)d_ws;
  float* h = (float*)(ws + 0);
  float* hn = (float*)(ws + 51200000);
  int* deg = (int*)(ws + 102400000);
  float* inv_deg = (float*)(ws + 102800000);
  int* row_start = (int*)(ws + 103200000);
  int* cursor = (int*)(ws + 103600016);
  int* csr_src = (int*)(ws + 104000016);
  int* bsums = (int*)(ws + 110400016);
  int* boffs = (int*)(ws + 110400272);

  hipMemsetAsync(deg, 0, N_NODES * sizeof(int), stream);
  k_degree<<<N_RANGES * FILL_CHUNKS, 256, 0, stream>>>(dst, deg);
  k_scanA<<<SCAN_BLOCKS, 256, 0, stream>>>(deg, row_start, bsums);
  k_scanB<<<1, 64, 0, stream>>>(bsums, boffs);
  k_scanC<<<SCAN_BLOCKS, 256, 0, stream>>>(deg, row_start, cursor, inv_deg, boffs);
  k_fill<<<N_RANGES * FILL_CHUNKS, 256, 0, stream>>>(src, dst, cursor, csr_src);

  // input projection: h = features @ W_in^T + b_in   (782 = ceil(100000/128))
  k_gemm<IN_FEATS, 0, false><<<782, 256, 0, stream>>>(features, nullptr, W_in,
                                                      nullptr, b_in, h);
  for (int l = 0; l < 2; ++l) {
    k_agg<<<12500, 256, 0, stream>>>(h, row_start, csr_src, inv_deg, hn);
    k_gemm<HIDDEN, HIDDEN, true><<<782, 256, 0, stream>>>(
        h, hn, W_self + l * HIDDEN * HIDDEN, W_neigh + l * HIDDEN * HIDDEN,
        b_self + l * HIDDEN, h);
  }
  k_out<<<25000, 256, 0, stream>>>(h, W_out, b_out, out);
}

// Round 8
// 722.709 us; speedup vs baseline: 1.4560x; 1.1435x over previous
//
#include <hip/hip_runtime.h>

// GraphSAGE fwd: h=XW_in^T+b; deg; 2x [agg(mean) -> h@Ws^T+b+hn@Wn^T -> lrelu]; out=h@Wo^T+bo
// GEMMs via split-bf16 MFMA. CSR build via XCD-local ranged scatter (R2).
// R5: aggregation gathers fp16 shadow of h (written by GEMM epilogue) -> halves
// the 819MB logical gather traffic; fp32 accumulate keeps error ~5e-4.
// ws layout (bytes):
//   h        : 0            .. 51,200,000   (100000*128 f32)
//   hn       : 51,200,000   .. 102,400,000
//   deg(int) : 102,400,000  .. 102,800,000
//   inv_deg  : 102,800,000  .. 103,200,000
//   row_start: 103,200,000  .. 103,600,016  (100001 ints, padded)
//   cursor   : 103,600,016  .. 104,000,016
//   csr_src  : 104,000,016  .. 110,400,016  (1.6M ints)
//   bsums    : 110,400,016  .. +256
//   boffs    : 110,400,272  .. +256
//   h_f16    : 110,401,024  .. 136,001,024  (100000*128 f16)

#define N_NODES 100000
#define N_EDGES 1600000
#define IN_FEATS 512
#define HIDDEN 128
#define NEG_SLOPE 0.01f
#define SCAN_BLOCKS 49  // ceil(100000/2048)

#define N_RANGES 8
#define RANGE_SZ 12500        // nodes per range (100000/8)
#define FILL_CHUNKS 256       // chunks per range
#define FILL_CHUNK 6250       // edges per chunk (1600000/256)

typedef __attribute__((ext_vector_type(8))) __bf16 bf16x8;
typedef __attribute__((ext_vector_type(4))) float f32x4;
typedef __attribute__((ext_vector_type(8))) _Float16 half8;

// degree count, XCD-local: block (r = b&7, c = b>>3) filters dst in range r
__global__ __launch_bounds__(256) void k_degree(const int* __restrict__ dst,
                                                int* __restrict__ deg) {
  int r = blockIdx.x & 7;
  int c = blockIdx.x >> 3;
  int lo = r * RANGE_SZ, hi = lo + RANGE_SZ;
  int e0 = c * FILL_CHUNK;
  int e1 = e0 + FILL_CHUNK;
  if (e1 > N_EDGES) e1 = N_EDGES;
  for (int e = e0 + threadIdx.x; e < e1; e += 256) {
    int d = dst[e];
    if (d >= lo && d < hi) atomicAdd(&deg[d], 1);
  }
}

__device__ __forceinline__ int wave_incl_scan(int v) {
  #pragma unroll
  for (int d = 1; d < 64; d <<= 1) {
    int t = __shfl_up(v, d, 64);
    if ((threadIdx.x & 63) >= d) v += t;
  }
  return v;
}

__global__ __launch_bounds__(256) void k_scanA(const int* __restrict__ deg,
                                               int* __restrict__ out,
                                               int* __restrict__ bsums) {
  __shared__ int wsum[4];
  int base = blockIdx.x * 2048 + threadIdx.x * 8;
  int v[8];
  int s = 0;
  #pragma unroll
  for (int i = 0; i < 8; i++) {
    int idx = base + i;
    v[i] = (idx < N_NODES) ? deg[idx] : 0;
    s += v[i];
  }
  int incl = wave_incl_scan(s);
  int wid = threadIdx.x >> 6;
  if ((threadIdx.x & 63) == 63) wsum[wid] = incl;
  __syncthreads();
  int woff = 0;
  #pragma unroll
  for (int w = 0; w < 4; w++)
    if (w < wid) woff += wsum[w];
  int run = woff + incl - s;
  #pragma unroll
  for (int i = 0; i < 8; i++) {
    int idx = base + i;
    if (idx < N_NODES) out[idx] = run;
    run += v[i];
  }
  if (threadIdx.x == 255) bsums[blockIdx.x] = woff + incl;
}

__global__ __launch_bounds__(64) void k_scanB(const int* __restrict__ bsums,
                                              int* __restrict__ boffs) {
  int t = threadIdx.x;
  int v = (t < SCAN_BLOCKS) ? bsums[t] : 0;
  int incl = wave_incl_scan(v);
  if (t < SCAN_BLOCKS) boffs[t] = incl - v;
}

__global__ __launch_bounds__(256) void k_scanC(const int* __restrict__ deg,
                                               int* __restrict__ row_start,
                                               int* __restrict__ cursor,
                                               float* __restrict__ inv_deg,
                                               const int* __restrict__ boffs) {
  int b = boffs[blockIdx.x];
  int base = blockIdx.x * 2048 + threadIdx.x * 8;
  #pragma unroll
  for (int i = 0; i < 8; i++) {
    int idx = base + i;
    if (idx < N_NODES) {
      int rs = row_start[idx] + b;
      row_start[idx] = rs;
      cursor[idx] = rs;
      int d = deg[idx];
      inv_deg[idx] = 1.0f / (float)(d > 1 ? d : 1);
    }
  }
  if (blockIdx.x == 0 && threadIdx.x == 0) row_start[N_NODES] = N_EDGES;
}

// CSR bucket fill, XCD-local (same ranged structure as k_degree)
__global__ __launch_bounds__(256) void k_fill(const int* __restrict__ src,
                                              const int* __restrict__ dst,
                                              int* __restrict__ cursor,
                                              int* __restrict__ csr_src) {
  int r = blockIdx.x & 7;
  int c = blockIdx.x >> 3;
  int lo = r * RANGE_SZ, hi = lo + RANGE_SZ;
  int e0 = c * FILL_CHUNK;
  int e1 = e0 + FILL_CHUNK;
  if (e1 > N_EDGES) e1 = N_EDGES;
  for (int e = e0 + threadIdx.x; e < e1; e += 256) {
    int d = dst[e];
    if (d >= lo && d < hi) {
      int p = atomicAdd(&cursor[d], 1);
      csr_src[p] = src[e];
    }
  }
}

// ---------------- split-bf16 MFMA GEMM ----------------
// C[i][col] = sum_k A[i][k]*W[col][k] + bias[col], optional leaky-relu.
// Virtual K = K1 (A1/W1) then K2 (A2/W2). BM=128, BN=128(=full N), BK=32.
// 4 waves in 2x2; each wave 64x64 = 4x4 frags of mfma_f32_16x16x32_bf16.
// fp32 -> (hi,lo) bf16 split during staging; 3 MFMAs per (a,b) frag pair.
// WF16: also write fp16 shadow of C (feeds the aggregation gather).
template <int K1, int K2, bool RELU, bool WF16>
__global__ __launch_bounds__(256) void k_gemm(const float* __restrict__ A1,
                                              const float* __restrict__ A2,
                                              const float* __restrict__ W1,
                                              const float* __restrict__ W2,
                                              const float* __restrict__ bias,
                                              float* __restrict__ C,
                                              _Float16* __restrict__ C16) {
  constexpr int BK = 32;
  constexpr int KT = (K1 + K2) / BK;
  constexpr int LP = 40;  // padded row length in bf16
  __shared__ __bf16 As_h[128 * LP];
  __shared__ __bf16 As_l[128 * LP];
  __shared__ __bf16 Bs_h[128 * LP];
  __shared__ __bf16 Bs_l[128 * LP];

  const int tid = threadIdx.x;
  const int lane = tid & 63;
  const int wid = tid >> 6;
  const int wr = wid >> 1;   // wave row (0..1) -> 64-row half
  const int wc = wid & 1;    // wave col (0..1) -> 64-col half
  const int lr = lane & 15;  // row/col within 16x16 frag
  const int kg = lane >> 4;  // k-group: lane reads k = 8*kg..8*kg+7
  const int r0 = blockIdx.x * 128;

  f32x4 acc[4][4];
  #pragma unroll
  for (int m = 0; m < 4; m++)
    #pragma unroll
    for (int n = 0; n < 4; n++) acc[m][n] = (f32x4){0.f, 0.f, 0.f, 0.f};

  float4 ra[4], rb[4];

  auto load_tile = [&](int kt) {
    const float* Ap;
    const float* Wp;
    int k0, lda;
    if (K2 == 0 || kt * BK < K1) {
      Ap = A1; Wp = W1; k0 = kt * BK; lda = K1;
    } else {
      Ap = A2; Wp = W2; k0 = kt * BK - K1; lda = K2;
    }
    #pragma unroll
    for (int i = 0; i < 4; i++) {
      int flat = i * 256 + tid;
      int row = flat >> 3;   // 0..127
      int q = flat & 7;      // float4 index within 32-k row
      int gr = r0 + row;
      ra[i] = (gr < N_NODES) ? *(const float4*)&Ap[(long)gr * lda + k0 + q * 4]
                             : make_float4(0.f, 0.f, 0.f, 0.f);
      rb[i] = *(const float4*)&Wp[(long)row * lda + k0 + q * 4];
    }
  };

  auto split_write = [&](float v, __bf16* hp, __bf16* lp, int off) {
    __bf16 h = (__bf16)v;
    float rem = v - (float)h;
    hp[off] = h;
    lp[off] = (__bf16)rem;
  };

  load_tile(0);

  for (int kt = 0; kt < KT; ++kt) {
    if (kt > 0) __syncthreads();  // prior compute done reading LDS
    #pragma unroll
    for (int i = 0; i < 4; i++) {
      int flat = i * 256 + tid;
      int row = flat >> 3;
      int q = flat & 7;
      int off = row * LP + q * 4;
      split_write(ra[i].x, As_h, As_l, off + 0);
      split_write(ra[i].y, As_h, As_l, off + 1);
      split_write(ra[i].z, As_h, As_l, off + 2);
      split_write(ra[i].w, As_h, As_l, off + 3);
      split_write(rb[i].x, Bs_h, Bs_l, off + 0);
      split_write(rb[i].y, Bs_h, Bs_l, off + 1);
      split_write(rb[i].z, Bs_h, Bs_l, off + 2);
      split_write(rb[i].w, Bs_h, Bs_l, off + 3);
    }
    __syncthreads();
    if (kt + 1 < KT) load_tile(kt + 1);  // prefetch next tile (hides HBM under MFMA)

    bf16x8 ah[4], al[4];
    #pragma unroll
    for (int m = 0; m < 4; m++) {
      int arow = wr * 64 + m * 16 + lr;
      ah[m] = *(const bf16x8*)&As_h[arow * LP + kg * 8];
      al[m] = *(const bf16x8*)&As_l[arow * LP + kg * 8];
    }
    #pragma unroll
    for (int n = 0; n < 4; n++) {
      int bcol = wc * 64 + n * 16 + lr;
      bf16x8 bh = *(const bf16x8*)&Bs_h[bcol * LP + kg * 8];
      bf16x8 bl = *(const bf16x8*)&Bs_l[bcol * LP + kg * 8];
      #pragma unroll
      for (int m = 0; m < 4; m++) {
        acc[m][n] = __builtin_amdgcn_mfma_f32_16x16x32_bf16(ah[m], bh, acc[m][n], 0, 0, 0);
        acc[m][n] = __builtin_amdgcn_mfma_f32_16x16x32_bf16(al[m], bh, acc[m][n], 0, 0, 0);
        acc[m][n] = __builtin_amdgcn_mfma_f32_16x16x32_bf16(ah[m], bl, acc[m][n], 0, 0, 0);
      }
    }
  }

  // epilogue: C[row][col], col = lane&15 (+16n+64wc), row = 4*(lane>>4)+j (+16m+64wr)
  #pragma unroll
  for (int n = 0; n < 4; n++) {
    int col = wc * 64 + n * 16 + lr;
    float bc = bias[col];
    #pragma unroll
    for (int m = 0; m < 4; m++) {
      int rowb = r0 + wr * 64 + m * 16 + kg * 4;
      #pragma unroll
      for (int j = 0; j < 4; j++) {
        int row = rowb + j;
        if (row < N_NODES) {
          float v = acc[m][n][j] + bc;
          if (RELU) v = v > 0.f ? v : v * NEG_SLOPE;
          C[(long)row * 128 + col] = v;
          if (WF16) C16[(long)row * 128 + col] = (_Float16)v;
        }
      }
    }
  }
}

// mean aggregation over fp16 shadow: 16 nodes/block, 16 lanes/node,
// half8 (16B) per lane, fp32 accumulate, x4 edge unroll for MLP.
__global__ __launch_bounds__(256) void k_agg(const _Float16* __restrict__ h16,
                                             const int* __restrict__ row_start,
                                             const int* __restrict__ csr_src,
                                             const float* __restrict__ inv_deg,
                                             float* __restrict__ hn) {
  int node = blockIdx.x * 16 + (threadIdx.x >> 4);
  int lane = threadIdx.x & 15;
  int s = row_start[node];
  int e = row_start[node + 1];
  float acc[8];
  #pragma unroll
  for (int j = 0; j < 8; j++) acc[j] = 0.f;

  int i = s;
  for (; i + 4 <= e; i += 4) {
    int s0 = csr_src[i + 0];
    int s1 = csr_src[i + 1];
    int s2 = csr_src[i + 2];
    int s3 = csr_src[i + 3];
    half8 v0 = *(const half8*)&h16[(long)s0 * HIDDEN + lane * 8];
    half8 v1 = *(const half8*)&h16[(long)s1 * HIDDEN + lane * 8];
    half8 v2 = *(const half8*)&h16[(long)s2 * HIDDEN + lane * 8];
    half8 v3 = *(const half8*)&h16[(long)s3 * HIDDEN + lane * 8];
    #pragma unroll
    for (int j = 0; j < 8; j++)
      acc[j] += ((float)v0[j] + (float)v1[j]) + ((float)v2[j] + (float)v3[j]);
  }
  for (; i < e; ++i) {
    int sn = csr_src[i];
    half8 v = *(const half8*)&h16[(long)sn * HIDDEN + lane * 8];
    #pragma unroll
    for (int j = 0; j < 8; j++) acc[j] += (float)v[j];
  }

  float id = inv_deg[node];
  float4 o0, o1;
  o0.x = acc[0] * id; o0.y = acc[1] * id; o0.z = acc[2] * id; o0.w = acc[3] * id;
  o1.x = acc[4] * id; o1.y = acc[5] * id; o1.z = acc[6] * id; o1.w = acc[7] * id;
  *(float4*)&hn[(long)node * HIDDEN + lane * 8 + 0] = o0;
  *(float4*)&hn[(long)node * HIDDEN + lane * 8 + 4] = o1;
}

// out[n][c] = h[n] . W_out[c] + b_out[c]; wave per node (4/block)
__global__ __launch_bounds__(256) void k_out(const float* __restrict__ h,
                                             const float* __restrict__ W_out,
                                             const float* __restrict__ b_out,
                                             float* __restrict__ out) {
  int node = blockIdx.x * 4 + (threadIdx.x >> 6);
  int l = threadIdx.x & 63;
  float a = h[node * HIDDEN + l];
  float b = h[node * HIDDEN + 64 + l];
  float s0 = a * W_out[l] + b * W_out[64 + l];
  float s1 = a * W_out[128 + l] + b * W_out[192 + l];
  #pragma unroll
  for (int d = 32; d >= 1; d >>= 1) {
    s0 += __shfl_xor(s0, d, 64);
    s1 += __shfl_xor(s1, d, 64);
  }
  if (l == 0) {
    out[node * 2 + 0] = s0 + b_out[0];
    out[node * 2 + 1] = s1 + b_out[1];
  }
}

extern "C" void kernel_launch(void* const* d_in, const int* in_sizes, int n_in,
                              void* d_out, int out_size, void* d_ws, size_t ws_size,
                              hipStream_t stream) {
  const float* features = (const float*)d_in[0];
  const int* src = (const int*)d_in[1];
  const int* dst = (const int*)d_in[2];
  const float* W_in = (const float*)d_in[3];
  const float* b_in = (const float*)d_in[4];
  const float* W_self = (const float*)d_in[5];
  const float* b_self = (const float*)d_in[6];
  const float* W_neigh = (const float*)d_in[7];
  const float* W_out = (const float*)d_in[8];
  const float* b_out = (const float*)d_in[9];
  float* out = (float*)d_out;

  char* ws = (char*)d_ws;
  float* h = (float*)(ws + 0);
  float* hn = (float*)(ws + 51200000);
  int* deg = (int*)(ws + 102400000);
  float* inv_deg = (float*)(ws + 102800000);
  int* row_start = (int*)(ws + 103200000);
  int* cursor = (int*)(ws + 103600016);
  int* csr_src = (int*)(ws + 104000016);
  int* bsums = (int*)(ws + 110400016);
  int* boffs = (int*)(ws + 110400272);
  _Float16* h16 = (_Float16*)(ws + 110401024);

  hipMemsetAsync(deg, 0, N_NODES * sizeof(int), stream);
  k_degree<<<N_RANGES * FILL_CHUNKS, 256, 0, stream>>>(dst, deg);
  k_scanA<<<SCAN_BLOCKS, 256, 0, stream>>>(deg, row_start, bsums);
  k_scanB<<<1, 64, 0, stream>>>(bsums, boffs);
  k_scanC<<<SCAN_BLOCKS, 256, 0, stream>>>(deg, row_start, cursor, inv_deg, boffs);
  k_fill<<<N_RANGES * FILL_CHUNKS, 256, 0, stream>>>(src, dst, cursor, csr_src);

  // input projection: h = features @ W_in^T + b_in   (782 = ceil(100000/128))
  k_gemm<IN_FEATS, 0, false, true><<<782, 256, 0, stream>>>(
      features, nullptr, W_in, nullptr, b_in, h, h16);

  // layer 0 (writes fp16 shadow for layer-1 agg)
  k_agg<<<6250, 256, 0, stream>>>(h16, row_start, csr_src, inv_deg, hn);
  k_gemm<HIDDEN, HIDDEN, true, true><<<782, 256, 0, stream>>>(
      h, hn, W_self, W_neigh, b_self, h, h16);

  // layer 1 (no shadow needed)
  k_agg<<<6250, 256, 0, stream>>>(h16, row_start, csr_src, inv_deg, hn);
  k_gemm<HIDDEN, HIDDEN, true, false><<<782, 256, 0, stream>>>(
      h, hn, W_self + HIDDEN * HIDDEN, W_neigh + HIDDEN * HIDDEN,
      b_self + HIDDEN, h, nullptr);

  k_out<<<25000, 256, 0, stream>>>(h, W_out, b_out, out);
}